// Round 4
// baseline (1684.195 us; speedup 1.0000x reference)
//
#include <hip/hip_runtime.h>
#include <hip/hip_bf16.h>

// ELSA block. Inputs: float32. Output: float32. Internal: bf16 (MFMA).
// Pipeline:
//  k_prep: weight repack f32->bf16 (interleave q/k rows, pad, fold ghost)
//  k_ln:   LayerNorm, x (B,C,D,H,W) f32 -> xn_t (frame*pix, 96) bf16
//  k_gemm<0>: qkv projection (MFMA) -> h=(q*k*scale) (f,c,p), v (f,c,p) bf16
//  k_conv: grouped 7x7 conv + exact GELU -> a_t (frame*pix, 96) bf16
//  per frame f (16x):  k_gemm<1>: 294-ch logits + ghost -> attn_f (294,p)
//                      k_aggr: 49-tap window aggregation -> out_t rows of f
//  k_gemm<2>: out proj + bias + f32 residual -> d_out f32 (B,C,D,H,W)
// Workspace (bytes), total 90,504,192 (~86.3 MB), weights first:
//  [0)        W2 (320x96 bf16)  61,440
//  [61440)    bias2 (320 f32)    1,280
//  [62720)    WA2 (320x96 bf16) 61,440
//  [124160)   biasA2 (320 f32)   1,280
//  [125440)   WP (128x96 bf16)  24,576
//  [150016)   biasP (128 f32)      512
//  [150528)   xn_t / a_t   28,311,552
//  [28462080) h / out_t    28,311,552
//  [56773632) v            28,311,552
//  [85085184) attn_f (294x9216 bf16) 5,419,008

typedef unsigned short u16;
typedef short bf16x8 __attribute__((ext_vector_type(8)));
typedef float floatx4 __attribute__((ext_vector_type(4)));
typedef unsigned short ushort8 __attribute__((ext_vector_type(8)));
typedef unsigned int uint4v __attribute__((ext_vector_type(4)));

#define PIX      9216
#define SCALE_QK 0.25f

__device__ __forceinline__ float b2f(u16 u) {
  union { unsigned int i; float f; } z; z.i = ((unsigned int)u) << 16; return z.f;
}
__device__ __forceinline__ u16 f2b(float f) {
  union { float f; unsigned int i; } z; z.f = f;
  unsigned int r = z.i + 0x7fffu + ((z.i >> 16) & 1u);
  return (u16)(r >> 16);
}

// ---------------- weight prep (f32 in, bf16/f32 out) ----------------
// W2 rows: [0,192) interleaved (q0,k0,q1,k1,...) from w_qk; [192,288) w_v; [288,320)=0
// WA2 rows: [0,294) w_a2*g_mul; rest 0. biasA2 = b_a2*g_mul + g_add.
// WP rows: [0,96) w_p; rest 0.
__global__ void k_prep(const float* __restrict__ w_qk, const float* __restrict__ b_qk,
                       const float* __restrict__ w_v,  const float* __restrict__ b_v,
                       const float* __restrict__ w_a2, const float* __restrict__ b_a2,
                       const float* __restrict__ g_mul,const float* __restrict__ g_add,
                       const float* __restrict__ w_p,  const float* __restrict__ b_p,
                       u16* __restrict__ W2, float* __restrict__ bias2,
                       u16* __restrict__ WA2, float* __restrict__ biasA2,
                       u16* __restrict__ WP, float* __restrict__ biasP) {
  int i = blockIdx.x * 256 + threadIdx.x;
  if (i < 30720) {                       // W2: 320*96
    int r = i / 96, ci = i % 96;
    float val = 0.f;
    if (r < 192) { int src = (r & 1) ? (96 + (r >> 1)) : (r >> 1); val = w_qk[src * 96 + ci]; }
    else if (r < 288) val = w_v[(r - 192) * 96 + ci];
    W2[i] = f2b(val);
  } else if (i < 31040) {                // bias2: 320
    int r = i - 30720; float bv = 0.f;
    if (r < 192) { int src = (r & 1) ? (96 + (r >> 1)) : (r >> 1); bv = b_qk[src]; }
    else if (r < 288) bv = b_v[r - 192];
    bias2[r] = bv;
  } else if (i < 61760) {                // WA2: 320*96
    int j = i - 31040; int r = j / 96, ci = j % 96;
    float wv = 0.f;
    if (r < 294) wv = w_a2[r * 96 + ci] * g_mul[r];
    WA2[j] = f2b(wv);
  } else if (i < 62080) {                // biasA2: 320
    int r = i - 61760; float bv = 0.f;
    if (r < 294) bv = b_a2[r] * g_mul[r] + g_add[r];
    biasA2[r] = bv;
  } else if (i < 74368) {                // WP: 128*96
    int j = i - 62080; int r = j / 96;
    WP[j] = (r < 96) ? f2b(w_p[j]) : (u16)0;
  } else if (i < 74496) {                // biasP: 128
    int r = i - 74368;
    biasP[r] = (r < 96) ? b_p[r] : 0.f;
  }
}

// ---------------- LayerNorm ----------------
// x: (B=2, C=96, D=8, 96, 96) f32. frame f = b*8+d, pixel p.
// out: xn_t[(f*9216+p)*96 + c] bf16
__global__ __launch_bounds__(256) void k_ln(const float* __restrict__ x,
                                            const float* __restrict__ lg,
                                            const float* __restrict__ lb,
                                            u16* __restrict__ xn) {
  int idx = blockIdx.x * 256 + threadIdx.x;    // 0..147455
  int f = idx / PIX, p = idx % PIX;
  int b = f >> 3, d = f & 7;
  size_t base = ((size_t)(b * 768 + d)) * PIX + p;  // + c*73728
  float s = 0.f, ss = 0.f;
  for (int c = 0; c < 96; ++c) {
    float v = x[base + (size_t)c * 73728];
    s += v; ss += v * v;
  }
  float mu = s * (1.f / 96.f);
  float var = ss * (1.f / 96.f) - mu * mu;
  float rs = rsqrtf(var + 1e-5f);
  size_t ob = (size_t)idx * 96;
  for (int c0 = 0; c0 < 96; c0 += 8) {
    ushort8 pack;
    for (int u = 0; u < 8; ++u) {
      int c = c0 + u;
      float v = x[base + (size_t)c * 73728];
      pack[u] = f2b((v - mu) * rs * lg[c] + lb[c]);
    }
    *(ushort8*)&xn[ob + c0] = pack;
  }
}

// ---------------- MFMA GEMM (64co x 64p tile, K=96) ----------------
// X: (f*9216+p, 96) bf16 rows. W: (rows, 96) bf16 padded. bias: f32.
// MODE 0: qkv -> h (out0), v (out1), grid.z=frames.
// MODE 1: attn_f (out0, single frame fArg, layout (row, pix)).
// MODE 2: final f32 (outF = d_out), resid = x f32, grid.z=frames.
template <int MODE>
__global__ __launch_bounds__(256) void k_gemm(const u16* __restrict__ X,
                                              const u16* __restrict__ W,
                                              const float* __restrict__ bias,
                                              u16* __restrict__ out0,
                                              u16* __restrict__ out1,
                                              float* __restrict__ outF,
                                              const float* __restrict__ resid,
                                              int fArg) {
  __shared__ u16 lw[64 * 104];   // row stride 104 bf16 (208B): 16B aligned
  __shared__ u16 lx[64 * 104];
  const int tid = threadIdx.x;
  const int f = (MODE == 1) ? fArg : blockIdx.z;
  const int p0 = blockIdx.x * 64;
  const int cot = blockIdx.y;

  for (int ch = tid; ch < 768; ch += 256) {
    int r = ch / 12, s2 = ch % 12;
    *(uint4v*)&lw[r * 104 + s2 * 8] = *(const uint4v*)&W[(size_t)(cot * 64 + r) * 96 + s2 * 8];
    *(uint4v*)&lx[r * 104 + s2 * 8] = *(const uint4v*)&X[((size_t)(f * PIX + p0 + r)) * 96 + s2 * 8];
  }
  __syncthreads();

  const int lane = tid & 63, wv = tid >> 6;
  const int cw = (wv >> 1) * 32, pw = (wv & 1) * 32;
  const int m = lane & 15, quad = lane >> 4;

  floatx4 acc[2][2] = {};
  for (int ks = 0; ks < 3; ++ks) {
    int ko = ks * 32 + quad * 8;
    bf16x8 a0 = *(const bf16x8*)&lw[(cw + m) * 104 + ko];
    bf16x8 a1 = *(const bf16x8*)&lw[(cw + 16 + m) * 104 + ko];
    bf16x8 b0 = *(const bf16x8*)&lx[(pw + m) * 104 + ko];
    bf16x8 b1 = *(const bf16x8*)&lx[(pw + 16 + m) * 104 + ko];
    acc[0][0] = __builtin_amdgcn_mfma_f32_16x16x32_bf16(a0, b0, acc[0][0], 0, 0, 0);
    acc[0][1] = __builtin_amdgcn_mfma_f32_16x16x32_bf16(a0, b1, acc[0][1], 0, 0, 0);
    acc[1][0] = __builtin_amdgcn_mfma_f32_16x16x32_bf16(a1, b0, acc[1][0], 0, 0, 0);
    acc[1][1] = __builtin_amdgcn_mfma_f32_16x16x32_bf16(a1, b1, acc[1][1], 0, 0, 0);
  }

  for (int mt = 0; mt < 2; ++mt)
    for (int nt = 0; nt < 2; ++nt) {
      int R = cot * 64 + cw + mt * 16 + quad * 4;   // padded row base (mult of 4)
      int pc = p0 + pw + nt * 16 + m;
      floatx4 v4 = acc[mt][nt];
      if (MODE == 0) {
        if (cot < 3) {   // interleaved q/k rows: (q_c, k_c, q_{c+1}, k_{c+1})
          float q0 = v4[0] + bias[R + 0], k0 = v4[1] + bias[R + 1];
          float q1 = v4[2] + bias[R + 2], k1 = v4[3] + bias[R + 3];
          int hc = R >> 1;
          out0[((size_t)f * 96 + hc) * PIX + pc]     = f2b(q0 * k0 * SCALE_QK);
          out0[((size_t)f * 96 + hc + 1) * PIX + pc] = f2b(q1 * k1 * SCALE_QK);
        } else {         // v rows
          for (int r = 0; r < 4; ++r) {
            int vr = R + r - 192;
            if (vr < 96) out1[((size_t)f * 96 + vr) * PIX + pc] = f2b(v4[r] + bias[R + r]);
          }
        }
      } else if (MODE == 1) {
        for (int r = 0; r < 4; ++r) {
          int o = R + r;
          if (o < 294) out0[(size_t)o * PIX + pc] = f2b(v4[r] + bias[o]);
        }
      } else {
        int b = f >> 3, d = f & 7;
        for (int r = 0; r < 4; ++r) {
          int o = R + r;
          if (o < 96) {
            size_t gi = ((size_t)(b * 96 + o) * 8 + d) * PIX + pc;
            outF[gi] = resid[gi] + v4[r] + bias[o];
          }
        }
      }
    }
}

// ---------------- grouped 7x7 conv + GELU ----------------
// h: (f, 96, 9216) bf16 -> a_t: (f*9216+p, 96) bf16.
__global__ __launch_bounds__(256) void k_conv(const u16* __restrict__ h,
                                              const float* __restrict__ w_a1,
                                              const float* __restrict__ b_a1,
                                              u16* __restrict__ a_t) {
  __shared__ float lwc[196];
  __shared__ float lbc;
  int co = blockIdx.x;
  int f = blockIdx.z;
  int tid = threadIdx.x;
  if (tid < 196) lwc[tid] = w_a1[co * 196 + tid];
  if (tid == 0) lbc = b_a1[co];
  __syncthreads();
  int p = blockIdx.y * 256 + tid;
  int y = p / 96, x0 = p % 96;
  float acc = lbc;
  int gb = (co >> 2) << 2;
  for (int g = 0; g < 4; ++g) {
    size_t cb = ((size_t)f * 96 + gb + g) * PIX;
    for (int i = 0; i < 7; ++i) {
      int yy = y + i - 3;
      if (yy < 0 || yy >= 96) continue;
      for (int j = 0; j < 7; ++j) {
        int xj = x0 + j - 3;
        if (xj < 0 || xj >= 96) continue;
        acc += lwc[g * 49 + i * 7 + j] * b2f(h[cb + yy * 96 + xj]);
      }
    }
  }
  float ge = 0.5f * acc * (1.f + erff(acc * 0.70710678118f));
  a_t[((size_t)f * PIX + p) * 96 + co] = f2b(ge);
}

// ---------------- 49-tap window aggregation (single frame) ----------------
// attn_f: (294, 9216), v: (f, 96, 9216) -> out_t rows of frame f
__global__ __launch_bounds__(256) void k_aggr(const u16* __restrict__ attn_f,
                                              const u16* __restrict__ v,
                                              u16* __restrict__ out_t,
                                              int f) {
  int c = blockIdx.x;
  int p = blockIdx.y * 256 + threadIdx.x;
  int y = p / 96, x0 = p % 96;
  int head = c >> 4;
  size_t ab = (size_t)(head * 49) * PIX + p;
  size_t vb = ((size_t)f * 96 + c) * PIX;
  float acc = 0.f;
  for (int i = 0; i < 7; ++i) {
    int yy = y + i - 3;
    if (yy < 0 || yy >= 96) continue;
    for (int j = 0; j < 7; ++j) {
      int xj = x0 + j - 3;
      if (xj < 0 || xj >= 96) continue;
      acc += b2f(attn_f[ab + (size_t)(i * 7 + j) * PIX]) * b2f(v[vb + yy * 96 + xj]);
    }
  }
  out_t[((size_t)f * PIX + p) * 96 + c] = f2b(acc);
}

extern "C" void kernel_launch(void* const* d_in, const int* in_sizes, int n_in,
                              void* d_out, int out_size, void* d_ws, size_t ws_size,
                              hipStream_t stream) {
  const float* x    = (const float*)d_in[0];
  const float* ln_g = (const float*)d_in[1];
  const float* ln_b = (const float*)d_in[2];
  const float* w_qk = (const float*)d_in[3];
  const float* b_qk = (const float*)d_in[4];
  const float* w_v  = (const float*)d_in[5];
  const float* b_v  = (const float*)d_in[6];
  const float* w_a1 = (const float*)d_in[7];
  const float* b_a1 = (const float*)d_in[8];
  const float* w_a2 = (const float*)d_in[9];
  const float* b_a2 = (const float*)d_in[10];
  const float* g_mul= (const float*)d_in[11];
  const float* g_add= (const float*)d_in[12];
  const float* w_p  = (const float*)d_in[13];
  const float* b_p  = (const float*)d_in[14];

  char* ws = (char*)d_ws;
  u16*   W2    = (u16*)(ws + 0);
  float* bias2 = (float*)(ws + 61440);
  u16*   WA2   = (u16*)(ws + 62720);
  float* biasA2= (float*)(ws + 124160);
  u16*   WP    = (u16*)(ws + 125440);
  float* biasP = (float*)(ws + 150016);
  u16*   xn_t  = (u16*)(ws + 150528);       // reused as a_t
  u16*   hbuf  = (u16*)(ws + 28462080);     // reused as out_t
  u16*   vbuf  = (u16*)(ws + 56773632);
  u16*   attnf = (u16*)(ws + 85085184);     // single-frame attn (294 x 9216)

  k_prep<<<291, 256, 0, stream>>>(w_qk, b_qk, w_v, b_v, w_a2, b_a2, g_mul, g_add,
                                  w_p, b_p, W2, bias2, WA2, biasA2, WP, biasP);
  k_ln<<<576, 256, 0, stream>>>(x, ln_g, ln_b, xn_t);
  k_gemm<0><<<dim3(144, 5, 16), 256, 0, stream>>>(xn_t, W2, bias2, hbuf, vbuf,
                                                  nullptr, nullptr, 0);
  k_conv<<<dim3(96, 36, 16), 256, 0, stream>>>(hbuf, w_a1, b_a1, xn_t /*a_t*/);
  for (int f = 0; f < 16; ++f) {
    k_gemm<1><<<dim3(144, 5, 1), 256, 0, stream>>>(xn_t /*a_t*/, WA2, biasA2,
                                                   attnf, nullptr, nullptr, nullptr, f);
    k_aggr<<<dim3(96, 36, 1), 256, 0, stream>>>(attnf, vbuf, hbuf /*out_t*/, f);
  }
  k_gemm<2><<<dim3(144, 2, 16), 256, 0, stream>>>(hbuf /*out_t*/, WP, biasP,
                                                  nullptr, nullptr, (float*)d_out, x, 0);
}

// Round 5
// 877.120 us; speedup vs baseline: 1.9201x; 1.9201x over previous
//
#include <hip/hip_runtime.h>
#include <hip/hip_bf16.h>

// ELSA block. Inputs: float32. Output: float32. Internal: bf16 (MFMA).
// Pipeline:
//  k_prep: weight repack f32->bf16 (interleave q/k rows, pad, fold ghost, swizzle conv w)
//  k_ln:   LayerNorm, x (B,C,D,H,W) f32 -> xn_t (frame*pix, 96) bf16
//  k_gemm<0>: qkv projection (MFMA) -> h=(q*k*scale) (f,c,p), v (f,c,p) bf16
//  k_conv: grouped 7x7 conv + exact GELU, sliding-window register-blocked
//  per frame f (16x):  k_gemm<1>: 294-ch logits + ghost -> attn_f (294,p)
//                      k_aggr: 49-tap window aggregation -> out_t rows of f
//  k_gemm<2>: out proj + bias + f32 residual -> d_out f32 (B,C,D,H,W)
// Workspace (bytes), total 90,579,456 (~86.4 MB):
//  [0)        W2 (320x96 bf16)  61,440
//  [61440)    bias2 (320 f32)    1,280
//  [62720)    WA2 (320x96 bf16) 61,440
//  [124160)   biasA2 (320 f32)   1,280
//  [125440)   WP (128x96 bf16)  24,576
//  [150016)   biasP (128 f32)      512
//  [150528)   WC1 (24x4x7x7x4 f32) 75,264
//  [225792)   xn_t / a_t   28,311,552
//  [28537344) h / out_t    28,311,552
//  [56848896) v            28,311,552
//  [85160448) attn_f (294x9216 bf16) 5,419,008

typedef unsigned short u16;
typedef short bf16x8 __attribute__((ext_vector_type(8)));
typedef float floatx4 __attribute__((ext_vector_type(4)));
typedef unsigned short ushort8 __attribute__((ext_vector_type(8)));
typedef unsigned short ushort4v __attribute__((ext_vector_type(4)));
typedef unsigned int uint4v __attribute__((ext_vector_type(4)));

#define PIX      9216
#define SCALE_QK 0.25f

__device__ __forceinline__ float b2f(u16 u) {
  union { unsigned int i; float f; } z; z.i = ((unsigned int)u) << 16; return z.f;
}
__device__ __forceinline__ float lo2f(unsigned int u) {
  union { unsigned int i; float f; } z; z.i = u << 16; return z.f;
}
__device__ __forceinline__ float hi2f(unsigned int u) {
  union { unsigned int i; float f; } z; z.i = u & 0xFFFF0000u; return z.f;
}
__device__ __forceinline__ u16 f2b(float f) {
  union { float f; unsigned int i; } z; z.f = f;
  unsigned int r = z.i + 0x7fffu + ((z.i >> 16) & 1u);
  return (u16)(r >> 16);
}

// ---------------- weight prep (f32 in, bf16/f32 out) ----------------
__global__ void k_prep(const float* __restrict__ w_qk, const float* __restrict__ b_qk,
                       const float* __restrict__ w_v,  const float* __restrict__ b_v,
                       const float* __restrict__ w_a1,
                       const float* __restrict__ w_a2, const float* __restrict__ b_a2,
                       const float* __restrict__ g_mul,const float* __restrict__ g_add,
                       const float* __restrict__ w_p,  const float* __restrict__ b_p,
                       u16* __restrict__ W2, float* __restrict__ bias2,
                       u16* __restrict__ WA2, float* __restrict__ biasA2,
                       u16* __restrict__ WP, float* __restrict__ biasP,
                       float* __restrict__ WC1) {
  int i = blockIdx.x * 256 + threadIdx.x;
  if (i < 30720) {                       // W2: 320*96
    int r = i / 96, ci = i % 96;
    float val = 0.f;
    if (r < 192) { int src = (r & 1) ? (96 + (r >> 1)) : (r >> 1); val = w_qk[src * 96 + ci]; }
    else if (r < 288) val = w_v[(r - 192) * 96 + ci];
    W2[i] = f2b(val);
  } else if (i < 31040) {                // bias2: 320
    int r = i - 30720; float bv = 0.f;
    if (r < 192) { int src = (r & 1) ? (96 + (r >> 1)) : (r >> 1); bv = b_qk[src]; }
    else if (r < 288) bv = b_v[r - 192];
    bias2[r] = bv;
  } else if (i < 61760) {                // WA2: 320*96
    int j = i - 31040; int r = j / 96, ci = j % 96;
    float wv = 0.f;
    if (r < 294) wv = w_a2[r * 96 + ci] * g_mul[r];
    WA2[j] = f2b(wv);
  } else if (i < 62080) {                // biasA2: 320
    int r = i - 61760; float bv = 0.f;
    if (r < 294) bv = b_a2[r] * g_mul[r] + g_add[r];
    biasA2[r] = bv;
  } else if (i < 74368) {                // WP: 128*96
    int j = i - 62080; int r = j / 96;
    WP[j] = (r < 96) ? f2b(w_p[j]) : (u16)0;
  } else if (i < 74496) {                // biasP: 128
    int r = i - 74368;
    biasP[r] = (r < 96) ? b_p[r] : 0.f;
  } else if (i < 93312) {                // WC1: [g][ch][ky][kx][co] f32, 18816
    int j = i - 74496;
    int co = j & 3, kx = (j >> 2) % 7, ky = (j / 28) % 7, ch = (j / 196) & 3, g = j / 784;
    WC1[j] = w_a1[(g * 4 + co) * 196 + ch * 49 + ky * 7 + kx];
  }
}

// ---------------- LayerNorm ----------------
__global__ __launch_bounds__(256) void k_ln(const float* __restrict__ x,
                                            const float* __restrict__ lg,
                                            const float* __restrict__ lb,
                                            u16* __restrict__ xn) {
  int idx = blockIdx.x * 256 + threadIdx.x;    // 0..147455
  int f = idx / PIX, p = idx % PIX;
  int b = f >> 3, d = f & 7;
  size_t base = ((size_t)(b * 768 + d)) * PIX + p;  // + c*73728
  float s = 0.f, ss = 0.f;
  for (int c = 0; c < 96; ++c) {
    float v = x[base + (size_t)c * 73728];
    s += v; ss += v * v;
  }
  float mu = s * (1.f / 96.f);
  float var = ss * (1.f / 96.f) - mu * mu;
  float rs = rsqrtf(var + 1e-5f);
  size_t ob = (size_t)idx * 96;
  for (int c0 = 0; c0 < 96; c0 += 8) {
    ushort8 pack;
    for (int u = 0; u < 8; ++u) {
      int c = c0 + u;
      float v = x[base + (size_t)c * 73728];
      pack[u] = f2b((v - mu) * rs * lg[c] + lb[c]);
    }
    *(ushort8*)&xn[ob + c0] = pack;
  }
}

// ---------------- MFMA GEMM (64co x 64p tile, K=96) ----------------
template <int MODE>
__global__ __launch_bounds__(256) void k_gemm(const u16* __restrict__ X,
                                              const u16* __restrict__ W,
                                              const float* __restrict__ bias,
                                              u16* __restrict__ out0,
                                              u16* __restrict__ out1,
                                              float* __restrict__ outF,
                                              const float* __restrict__ resid,
                                              int fArg) {
  __shared__ u16 lw[64 * 104];
  __shared__ u16 lx[64 * 104];
  const int tid = threadIdx.x;
  const int f = (MODE == 1) ? fArg : blockIdx.z;
  const int p0 = blockIdx.x * 64;
  const int cot = blockIdx.y;

  for (int ch = tid; ch < 768; ch += 256) {
    int r = ch / 12, s2 = ch % 12;
    *(uint4v*)&lw[r * 104 + s2 * 8] = *(const uint4v*)&W[(size_t)(cot * 64 + r) * 96 + s2 * 8];
    *(uint4v*)&lx[r * 104 + s2 * 8] = *(const uint4v*)&X[((size_t)(f * PIX + p0 + r)) * 96 + s2 * 8];
  }
  __syncthreads();

  const int lane = tid & 63, wv = tid >> 6;
  const int cw = (wv >> 1) * 32, pw = (wv & 1) * 32;
  const int m = lane & 15, quad = lane >> 4;

  floatx4 acc[2][2] = {};
  for (int ks = 0; ks < 3; ++ks) {
    int ko = ks * 32 + quad * 8;
    bf16x8 a0 = *(const bf16x8*)&lw[(cw + m) * 104 + ko];
    bf16x8 a1 = *(const bf16x8*)&lw[(cw + 16 + m) * 104 + ko];
    bf16x8 b0 = *(const bf16x8*)&lx[(pw + m) * 104 + ko];
    bf16x8 b1 = *(const bf16x8*)&lx[(pw + 16 + m) * 104 + ko];
    acc[0][0] = __builtin_amdgcn_mfma_f32_16x16x32_bf16(a0, b0, acc[0][0], 0, 0, 0);
    acc[0][1] = __builtin_amdgcn_mfma_f32_16x16x32_bf16(a0, b1, acc[0][1], 0, 0, 0);
    acc[1][0] = __builtin_amdgcn_mfma_f32_16x16x32_bf16(a1, b0, acc[1][0], 0, 0, 0);
    acc[1][1] = __builtin_amdgcn_mfma_f32_16x16x32_bf16(a1, b1, acc[1][1], 0, 0, 0);
  }

  for (int mt = 0; mt < 2; ++mt)
    for (int nt = 0; nt < 2; ++nt) {
      int R = cot * 64 + cw + mt * 16 + quad * 4;
      int pc = p0 + pw + nt * 16 + m;
      floatx4 v4 = acc[mt][nt];
      if (MODE == 0) {
        if (cot < 3) {
          float q0 = v4[0] + bias[R + 0], k0 = v4[1] + bias[R + 1];
          float q1 = v4[2] + bias[R + 2], k1 = v4[3] + bias[R + 3];
          int hc = R >> 1;
          out0[((size_t)f * 96 + hc) * PIX + pc]     = f2b(q0 * k0 * SCALE_QK);
          out0[((size_t)f * 96 + hc + 1) * PIX + pc] = f2b(q1 * k1 * SCALE_QK);
        } else {
          for (int r = 0; r < 4; ++r) {
            int vr = R + r - 192;
            if (vr < 96) out1[((size_t)f * 96 + vr) * PIX + pc] = f2b(v4[r] + bias[R + r]);
          }
        }
      } else if (MODE == 1) {
        for (int r = 0; r < 4; ++r) {
          int o = R + r;
          if (o < 294) out0[(size_t)o * PIX + pc] = f2b(v4[r] + bias[o]);
        }
      } else {
        int b = f >> 3, d = f & 7;
        for (int r = 0; r < 4; ++r) {
          int o = R + r;
          if (o < 96) {
            size_t gi = ((size_t)(b * 96 + o) * 8 + d) * PIX + pc;
            outF[gi] = resid[gi] + v4[r] + bias[o];
          }
        }
      }
    }
}

// ---------------- grouped 7x7 conv + GELU (sliding window) ----------------
// h: (f, 96, 9216) bf16 -> a_t: (f*9216+p, 96) bf16.
// block = (group g of 4 ch, 32-row tile, frame). thread = (y of 32, xseg of 12).
// weights from WC1 [g][ch][ky][kx][co] via wave-uniform s_loads (SGPR FMA operand).
__global__ __launch_bounds__(256) void k_conv(const u16* __restrict__ h,
                                              const float* __restrict__ wc1,
                                              const float* __restrict__ b_a1,
                                              u16* __restrict__ a_t) {
  __shared__ float li[4 * 38 * 104];   // 4 ch x rows y0-3..y0+34 x cols -3..100, 63.2KB
  const int g = blockIdx.x, ty = blockIdx.y, f = blockIdx.z;
  const int tid = threadIdx.x;
  const int gb = g * 4, y0 = ty * 32;
  for (int idx = tid; idx < 4 * 38 * 104; idx += 256) {
    int col = idx % 104;
    int rr = (idx / 104) % 38;
    int ch = idx / (104 * 38);
    int ax = col - 3, ay = y0 - 3 + rr;
    float v = 0.f;
    if (ax >= 0 && ax < 96 && ay >= 0 && ay < 96)
      v = b2f(h[((size_t)f * 96 + gb + ch) * PIX + ay * 96 + ax]);
    li[idx] = v;
  }
  __syncthreads();

  const int y = tid >> 3;            // 0..31
  const int x0 = (tid & 7) * 12;     // 0..84
  float acc[4][12];
  #pragma unroll
  for (int co = 0; co < 4; ++co) {
    float bv = b_a1[gb + co];
    #pragma unroll
    for (int o = 0; o < 12; ++o) acc[co][o] = bv;
  }

  for (int ch = 0; ch < 4; ++ch)
    for (int ky = 0; ky < 7; ++ky) {
      const float* wrow = &wc1[(((g * 4 + ch) * 7) + ky) * 28];
      float w[28];
      #pragma unroll
      for (int t = 0; t < 28; ++t) w[t] = wrow[t];
      const float* lrow = &li[(ch * 38 + (y + ky)) * 104 + x0];
      float in[18];
      #pragma unroll
      for (int t = 0; t < 18; ++t) in[t] = lrow[t];
      #pragma unroll
      for (int kx = 0; kx < 7; ++kx)
        #pragma unroll
        for (int o = 0; o < 12; ++o)
          #pragma unroll
          for (int co = 0; co < 4; ++co)
            acc[co][o] += w[kx * 4 + co] * in[o + kx];
    }

  size_t obase = ((size_t)f * PIX + (size_t)(y0 + y) * 96 + x0) * 96 + gb;
  #pragma unroll
  for (int o = 0; o < 12; ++o) {
    ushort4v r4;
    #pragma unroll
    for (int co = 0; co < 4; ++co) {
      float a = acc[co][o];
      float ge = 0.5f * a * (1.f + erff(a * 0.70710678118f));
      r4[co] = f2b(ge);
    }
    *(ushort4v*)&a_t[obase + (size_t)o * 96] = r4;
  }
}

// ---------------- 49-tap window aggregation (single frame, sliding window) ----
// attn_f: (294, 9216) bf16, v: (f, 96, 9216) bf16 -> out_t rows of frame f.
// block = (cquad of 4 ch, 16-row tile). thread = (y of 16, xseg of 6).
__global__ __launch_bounds__(256) void k_aggr(const u16* __restrict__ attn_f,
                                              const u16* __restrict__ v,
                                              u16* __restrict__ out_t,
                                              int f) {
  __shared__ u16 lv[4 * 22 * 104];   // 4 ch x rows y0-3..y0+18 x cols -3..100, 18.3KB
  const int cq = blockIdx.x, ty = blockIdx.y;
  const int tid = threadIdx.x;
  const int c0 = cq * 4, y0 = ty * 16;
  const int head = c0 >> 4;
  for (int idx = tid; idx < 4 * 22 * 104; idx += 256) {
    int col = idx % 104;
    int rr = (idx / 104) % 22;
    int ch = idx / (104 * 22);
    int ax = col - 3, ay = y0 - 3 + rr;
    u16 val = 0;
    if (ax >= 0 && ax < 96 && ay >= 0 && ay < 96)
      val = v[((size_t)f * 96 + c0 + ch) * PIX + ay * 96 + ax];
    lv[idx] = val;
  }
  __syncthreads();

  const int y = tid >> 4;            // 0..15
  const int x0 = (tid & 15) * 6;     // 0..90
  float acc[4][6] = {};
  const int prow = (y0 + y) * 96 + x0;

  for (int i = 0; i < 7; ++i) {
    float vrow[4][12];
    #pragma unroll
    for (int ch = 0; ch < 4; ++ch) {
      const unsigned int* lsrc = (const unsigned int*)&lv[(ch * 22 + (y + i)) * 104 + x0];
      #pragma unroll
      for (int t = 0; t < 6; ++t) {
        unsigned int u = lsrc[t];
        vrow[ch][2 * t]     = lo2f(u);
        vrow[ch][2 * t + 1] = hi2f(u);
      }
    }
    #pragma unroll
    for (int j = 0; j < 7; ++j) {
      const unsigned int* asrc =
          (const unsigned int*)&attn_f[(size_t)(head * 49 + i * 7 + j) * PIX + prow];
      unsigned int u0 = asrc[0], u1 = asrc[1], u2 = asrc[2];
      float av[6] = {lo2f(u0), hi2f(u0), lo2f(u1), hi2f(u1), lo2f(u2), hi2f(u2)};
      #pragma unroll
      for (int o = 0; o < 6; ++o)
        #pragma unroll
        for (int ch = 0; ch < 4; ++ch)
          acc[ch][o] += av[o] * vrow[ch][o + j];
    }
  }

  size_t obase = ((size_t)f * PIX + prow) * 96 + c0;
  #pragma unroll
  for (int o = 0; o < 6; ++o) {
    ushort4v r4;
    #pragma unroll
    for (int ch = 0; ch < 4; ++ch) r4[ch] = f2b(acc[ch][o]);
    *(ushort4v*)&out_t[obase + (size_t)o * 96] = r4;
  }
}

extern "C" void kernel_launch(void* const* d_in, const int* in_sizes, int n_in,
                              void* d_out, int out_size, void* d_ws, size_t ws_size,
                              hipStream_t stream) {
  const float* x    = (const float*)d_in[0];
  const float* ln_g = (const float*)d_in[1];
  const float* ln_b = (const float*)d_in[2];
  const float* w_qk = (const float*)d_in[3];
  const float* b_qk = (const float*)d_in[4];
  const float* w_v  = (const float*)d_in[5];
  const float* b_v  = (const float*)d_in[6];
  const float* w_a1 = (const float*)d_in[7];
  const float* b_a1 = (const float*)d_in[8];
  const float* w_a2 = (const float*)d_in[9];
  const float* b_a2 = (const float*)d_in[10];
  const float* g_mul= (const float*)d_in[11];
  const float* g_add= (const float*)d_in[12];
  const float* w_p  = (const float*)d_in[13];
  const float* b_p  = (const float*)d_in[14];

  char* ws = (char*)d_ws;
  u16*   W2    = (u16*)(ws + 0);
  float* bias2 = (float*)(ws + 61440);
  u16*   WA2   = (u16*)(ws + 62720);
  float* biasA2= (float*)(ws + 124160);
  u16*   WP    = (u16*)(ws + 125440);
  float* biasP = (float*)(ws + 150016);
  float* WC1   = (float*)(ws + 150528);
  u16*   xn_t  = (u16*)(ws + 225792);       // reused as a_t
  u16*   hbuf  = (u16*)(ws + 28537344);     // reused as out_t
  u16*   vbuf  = (u16*)(ws + 56848896);
  u16*   attnf = (u16*)(ws + 85160448);     // single-frame attn (294 x 9216)

  k_prep<<<365, 256, 0, stream>>>(w_qk, b_qk, w_v, b_v, w_a1, w_a2, b_a2, g_mul, g_add,
                                  w_p, b_p, W2, bias2, WA2, biasA2, WP, biasP, WC1);
  k_ln<<<576, 256, 0, stream>>>(x, ln_g, ln_b, xn_t);
  k_gemm<0><<<dim3(144, 5, 16), 256, 0, stream>>>(xn_t, W2, bias2, hbuf, vbuf,
                                                  nullptr, nullptr, 0);
  k_conv<<<dim3(24, 3, 16), 256, 0, stream>>>(hbuf, WC1, b_a1, xn_t /*a_t*/);
  for (int f = 0; f < 16; ++f) {
    k_gemm<1><<<dim3(144, 5, 1), 256, 0, stream>>>(xn_t /*a_t*/, WA2, biasA2,
                                                   attnf, nullptr, nullptr, nullptr, f);
    k_aggr<<<dim3(24, 6, 1), 256, 0, stream>>>(attnf, vbuf, hbuf /*out_t*/, f);
  }
  k_gemm<2><<<dim3(144, 2, 16), 256, 0, stream>>>(hbuf /*out_t*/, WP, biasP,
                                                  nullptr, nullptr, (float*)d_out, x, 0);
}

// Round 6
// 466.930 us; speedup vs baseline: 3.6069x; 1.8785x over previous
//
#include <hip/hip_runtime.h>
#include <hip/hip_bf16.h>

// ELSA block. Inputs: float32. Output: float32. Internal: bf16 (MFMA).
// Pipeline:
//  k_prep: weight repack f32->bf16 (interleave q/k rows, pad, fold ghost, swizzle conv w)
//  k_ln:   LayerNorm, x (B,C,D,H,W) f32 -> xn_t (frame*pix, 96) bf16
//  k_gemm<0>: qkv projection (MFMA) -> h=(q*k*scale) (f,c,p), v (f,c,p) bf16
//  k_conv: grouped 7x7 conv + exact GELU, sliding-window, bf16 LDS (occupancy!)
//  2 chunks of 8 frames:  k_gemm<1>: 294-ch logits + ghost -> attn_c (8f,294,p)
//                         k_aggr: 49-tap window aggregation -> out_t rows
//  k_gemm<2>: out proj + bias + f32 residual -> d_out f32 (B,C,D,H,W)
// Workspace (bytes), total 128,512,512 (~122.6 MB):
//  [0)        W2 (320x96 bf16)  61,440
//  [61440)    bias2 (320 f32)    1,280
//  [62720)    WA2 (320x96 bf16) 61,440
//  [124160)   biasA2 (320 f32)   1,280
//  [125440)   WP (128x96 bf16)  24,576
//  [150016)   biasP (128 f32)      512
//  [150528)   WC1 (24x4x7x7x4 f32) 75,264
//  [225792)   xn_t / a_t   28,311,552
//  [28537344) h / out_t    28,311,552
//  [56848896) v            28,311,552
//  [85160448) attn_c (8x294x9216 bf16) 43,352,064

typedef unsigned short u16;
typedef short bf16x8 __attribute__((ext_vector_type(8)));
typedef float floatx4 __attribute__((ext_vector_type(4)));
typedef unsigned short ushort8 __attribute__((ext_vector_type(8)));
typedef unsigned short ushort4v __attribute__((ext_vector_type(4)));
typedef unsigned int uint4v __attribute__((ext_vector_type(4)));

#define PIX      9216
#define SCALE_QK 0.25f

__device__ __forceinline__ float b2f(u16 u) {
  union { unsigned int i; float f; } z; z.i = ((unsigned int)u) << 16; return z.f;
}
__device__ __forceinline__ float lo2f(unsigned int u) {
  union { unsigned int i; float f; } z; z.i = u << 16; return z.f;
}
__device__ __forceinline__ float hi2f(unsigned int u) {
  union { unsigned int i; float f; } z; z.i = u & 0xFFFF0000u; return z.f;
}
__device__ __forceinline__ u16 f2b(float f) {
  union { float f; unsigned int i; } z; z.f = f;
  unsigned int r = z.i + 0x7fffu + ((z.i >> 16) & 1u);
  return (u16)(r >> 16);
}

// ---------------- weight prep (f32 in, bf16/f32 out) ----------------
__global__ void k_prep(const float* __restrict__ w_qk, const float* __restrict__ b_qk,
                       const float* __restrict__ w_v,  const float* __restrict__ b_v,
                       const float* __restrict__ w_a1,
                       const float* __restrict__ w_a2, const float* __restrict__ b_a2,
                       const float* __restrict__ g_mul,const float* __restrict__ g_add,
                       const float* __restrict__ w_p,  const float* __restrict__ b_p,
                       u16* __restrict__ W2, float* __restrict__ bias2,
                       u16* __restrict__ WA2, float* __restrict__ biasA2,
                       u16* __restrict__ WP, float* __restrict__ biasP,
                       float* __restrict__ WC1) {
  int i = blockIdx.x * 256 + threadIdx.x;
  if (i < 30720) {                       // W2: 320*96
    int r = i / 96, ci = i % 96;
    float val = 0.f;
    if (r < 192) { int src = (r & 1) ? (96 + (r >> 1)) : (r >> 1); val = w_qk[src * 96 + ci]; }
    else if (r < 288) val = w_v[(r - 192) * 96 + ci];
    W2[i] = f2b(val);
  } else if (i < 31040) {                // bias2: 320
    int r = i - 30720; float bv = 0.f;
    if (r < 192) { int src = (r & 1) ? (96 + (r >> 1)) : (r >> 1); bv = b_qk[src]; }
    else if (r < 288) bv = b_v[r - 192];
    bias2[r] = bv;
  } else if (i < 61760) {                // WA2: 320*96
    int j = i - 31040; int r = j / 96, ci = j % 96;
    float wv = 0.f;
    if (r < 294) wv = w_a2[r * 96 + ci] * g_mul[r];
    WA2[j] = f2b(wv);
  } else if (i < 62080) {                // biasA2: 320
    int r = i - 61760; float bv = 0.f;
    if (r < 294) bv = b_a2[r] * g_mul[r] + g_add[r];
    biasA2[r] = bv;
  } else if (i < 74368) {                // WP: 128*96
    int j = i - 62080; int r = j / 96;
    WP[j] = (r < 96) ? f2b(w_p[j]) : (u16)0;
  } else if (i < 74496) {                // biasP: 128
    int r = i - 74368;
    biasP[r] = (r < 96) ? b_p[r] : 0.f;
  } else if (i < 93312) {                // WC1: [g][ch][ky][kx][co] f32, 18816
    int j = i - 74496;
    int co = j & 3, kx = (j >> 2) % 7, ky = (j / 28) % 7, ch = (j / 196) & 3, g = j / 784;
    WC1[j] = w_a1[(g * 4 + co) * 196 + ch * 49 + ky * 7 + kx];
  }
}

// ---------------- LayerNorm ----------------
__global__ __launch_bounds__(256) void k_ln(const float* __restrict__ x,
                                            const float* __restrict__ lg,
                                            const float* __restrict__ lb,
                                            u16* __restrict__ xn) {
  int idx = blockIdx.x * 256 + threadIdx.x;    // 0..147455
  int f = idx / PIX, p = idx % PIX;
  int b = f >> 3, d = f & 7;
  size_t base = ((size_t)(b * 768 + d)) * PIX + p;  // + c*73728
  float s = 0.f, ss = 0.f;
  for (int c = 0; c < 96; ++c) {
    float v = x[base + (size_t)c * 73728];
    s += v; ss += v * v;
  }
  float mu = s * (1.f / 96.f);
  float var = ss * (1.f / 96.f) - mu * mu;
  float rs = rsqrtf(var + 1e-5f);
  size_t ob = (size_t)idx * 96;
  for (int c0 = 0; c0 < 96; c0 += 8) {
    ushort8 pack;
    for (int u = 0; u < 8; ++u) {
      int c = c0 + u;
      float v = x[base + (size_t)c * 73728];
      pack[u] = f2b((v - mu) * rs * lg[c] + lb[c]);
    }
    *(ushort8*)&xn[ob + c0] = pack;
  }
}

// ---------------- MFMA GEMM (64co x 64p tile, K=96) ----------------
// MODE 0: qkv -> h (out0), v (out1), f = blockIdx.z.
// MODE 1: attn chunk (out0, f = fArg + blockIdx.z, store frame-local z).
// MODE 2: final f32 (outF = d_out), resid = x f32, f = blockIdx.z.
template <int MODE>
__global__ __launch_bounds__(256) void k_gemm(const u16* __restrict__ X,
                                              const u16* __restrict__ W,
                                              const float* __restrict__ bias,
                                              u16* __restrict__ out0,
                                              u16* __restrict__ out1,
                                              float* __restrict__ outF,
                                              const float* __restrict__ resid,
                                              int fArg) {
  __shared__ u16 lw[64 * 104];
  __shared__ u16 lx[64 * 104];
  const int tid = threadIdx.x;
  const int fc = blockIdx.z;
  const int f = (MODE == 1) ? (fArg + fc) : fc;
  const int p0 = blockIdx.x * 64;
  const int cot = blockIdx.y;

  for (int ch = tid; ch < 768; ch += 256) {
    int r = ch / 12, s2 = ch % 12;
    *(uint4v*)&lw[r * 104 + s2 * 8] = *(const uint4v*)&W[(size_t)(cot * 64 + r) * 96 + s2 * 8];
    *(uint4v*)&lx[r * 104 + s2 * 8] = *(const uint4v*)&X[((size_t)(f * PIX + p0 + r)) * 96 + s2 * 8];
  }
  __syncthreads();

  const int lane = tid & 63, wv = tid >> 6;
  const int cw = (wv >> 1) * 32, pw = (wv & 1) * 32;
  const int m = lane & 15, quad = lane >> 4;

  floatx4 acc[2][2] = {};
  for (int ks = 0; ks < 3; ++ks) {
    int ko = ks * 32 + quad * 8;
    bf16x8 a0 = *(const bf16x8*)&lw[(cw + m) * 104 + ko];
    bf16x8 a1 = *(const bf16x8*)&lw[(cw + 16 + m) * 104 + ko];
    bf16x8 b0 = *(const bf16x8*)&lx[(pw + m) * 104 + ko];
    bf16x8 b1 = *(const bf16x8*)&lx[(pw + 16 + m) * 104 + ko];
    acc[0][0] = __builtin_amdgcn_mfma_f32_16x16x32_bf16(a0, b0, acc[0][0], 0, 0, 0);
    acc[0][1] = __builtin_amdgcn_mfma_f32_16x16x32_bf16(a0, b1, acc[0][1], 0, 0, 0);
    acc[1][0] = __builtin_amdgcn_mfma_f32_16x16x32_bf16(a1, b0, acc[1][0], 0, 0, 0);
    acc[1][1] = __builtin_amdgcn_mfma_f32_16x16x32_bf16(a1, b1, acc[1][1], 0, 0, 0);
  }

  for (int mt = 0; mt < 2; ++mt)
    for (int nt = 0; nt < 2; ++nt) {
      int R = cot * 64 + cw + mt * 16 + quad * 4;
      int pc = p0 + pw + nt * 16 + m;
      floatx4 v4 = acc[mt][nt];
      if (MODE == 0) {
        if (cot < 3) {
          float q0 = v4[0] + bias[R + 0], k0 = v4[1] + bias[R + 1];
          float q1 = v4[2] + bias[R + 2], k1 = v4[3] + bias[R + 3];
          int hc = R >> 1;
          out0[((size_t)f * 96 + hc) * PIX + pc]     = f2b(q0 * k0 * SCALE_QK);
          out0[((size_t)f * 96 + hc + 1) * PIX + pc] = f2b(q1 * k1 * SCALE_QK);
        } else {
          for (int r = 0; r < 4; ++r) {
            int vr = R + r - 192;
            if (vr < 96) out1[((size_t)f * 96 + vr) * PIX + pc] = f2b(v4[r] + bias[R + r]);
          }
        }
      } else if (MODE == 1) {
        for (int r = 0; r < 4; ++r) {
          int o = R + r;
          if (o < 294) out0[((size_t)fc * 294 + o) * PIX + pc] = f2b(v4[r] + bias[o]);
        }
      } else {
        int b = f >> 3, d = f & 7;
        for (int r = 0; r < 4; ++r) {
          int o = R + r;
          if (o < 96) {
            size_t gi = ((size_t)(b * 96 + o) * 8 + d) * PIX + pc;
            outF[gi] = resid[gi] + v4[r] + bias[o];
          }
        }
      }
    }
}

// ---------------- grouped 7x7 conv + GELU (sliding window, bf16 LDS) ----------
// h: (f, 96, 9216) bf16 -> a_t: (f*9216+p, 96) bf16.
// block = (group g of 4 ch, 32-row tile, frame). thread = (y of 32, xseg of 12).
// LDS staged as bf16 (31.6 KB -> ~5 blocks/CU); reads as dwords -> 16-bank spread.
__global__ __launch_bounds__(256) void k_conv(const u16* __restrict__ h,
                                              const float* __restrict__ wc1,
                                              const float* __restrict__ b_a1,
                                              u16* __restrict__ a_t) {
  __shared__ u16 li[4 * 38 * 104];   // 4 ch x rows y0-3..y0+34 x cols -3..100, 31.6KB
  const int g = blockIdx.x, ty = blockIdx.y, f = blockIdx.z;
  const int tid = threadIdx.x;
  const int gb = g * 4, y0 = ty * 32;
  for (int idx = tid; idx < 4 * 38 * 104; idx += 256) {
    int col = idx % 104;
    int rr = (idx / 104) % 38;
    int ch = idx / (104 * 38);
    int ax = col - 3, ay = y0 - 3 + rr;
    u16 v = 0;
    if (ax >= 0 && ax < 96 && ay >= 0 && ay < 96)
      v = h[((size_t)f * 96 + gb + ch) * PIX + ay * 96 + ax];
    li[idx] = v;
  }
  __syncthreads();

  const int y = tid >> 3;            // 0..31
  const int x0 = (tid & 7) * 12;     // 0..84 (even -> dword-aligned LDS reads)
  float acc[4][12];
  #pragma unroll
  for (int co = 0; co < 4; ++co) {
    float bv = b_a1[gb + co];
    #pragma unroll
    for (int o = 0; o < 12; ++o) acc[co][o] = bv;
  }

  for (int ch = 0; ch < 4; ++ch)
    for (int ky = 0; ky < 7; ++ky) {
      const float* wrow = &wc1[(((g * 4 + ch) * 7) + ky) * 28];
      float w[28];
      #pragma unroll
      for (int t = 0; t < 28; ++t) w[t] = wrow[t];
      const unsigned int* lsrc =
          (const unsigned int*)&li[(ch * 38 + (y + ky)) * 104 + x0];
      float in[18];
      #pragma unroll
      for (int t = 0; t < 9; ++t) {
        unsigned int u = lsrc[t];
        in[2 * t]     = lo2f(u);
        in[2 * t + 1] = hi2f(u);
      }
      #pragma unroll
      for (int kx = 0; kx < 7; ++kx)
        #pragma unroll
        for (int o = 0; o < 12; ++o)
          #pragma unroll
          for (int co = 0; co < 4; ++co)
            acc[co][o] += w[kx * 4 + co] * in[o + kx];
    }

  size_t obase = ((size_t)f * PIX + (size_t)(y0 + y) * 96 + x0) * 96 + gb;
  #pragma unroll
  for (int o = 0; o < 12; ++o) {
    ushort4v r4;
    #pragma unroll
    for (int co = 0; co < 4; ++co) {
      float a = acc[co][o];
      float ge = 0.5f * a * (1.f + erff(a * 0.70710678118f));
      r4[co] = f2b(ge);
    }
    *(ushort4v*)&a_t[obase + (size_t)o * 96] = r4;
  }
}

// ---------------- 49-tap window aggregation (8-frame chunk) ----------------
// attn_c: (8, 294, 9216) bf16, v: (f, 96, 9216) bf16 -> out_t rows.
// block = (cquad of 4 ch, 16-row tile, frame-in-chunk).
__global__ __launch_bounds__(256) void k_aggr(const u16* __restrict__ attn_c,
                                              const u16* __restrict__ v,
                                              u16* __restrict__ out_t,
                                              int fbase) {
  __shared__ u16 lv[4 * 22 * 104];   // 18.3KB
  const int cq = blockIdx.x, ty = blockIdx.y, fc = blockIdx.z;
  const int f = fbase + fc;
  const int tid = threadIdx.x;
  const int c0 = cq * 4, y0 = ty * 16;
  const int head = c0 >> 4;
  for (int idx = tid; idx < 4 * 22 * 104; idx += 256) {
    int col = idx % 104;
    int rr = (idx / 104) % 22;
    int ch = idx / (104 * 22);
    int ax = col - 3, ay = y0 - 3 + rr;
    u16 val = 0;
    if (ax >= 0 && ax < 96 && ay >= 0 && ay < 96)
      val = v[((size_t)f * 96 + c0 + ch) * PIX + ay * 96 + ax];
    lv[idx] = val;
  }
  __syncthreads();

  const int y = tid >> 4;            // 0..15
  const int x0 = (tid & 15) * 6;     // 0..90
  float acc[4][6] = {};
  const int prow = (y0 + y) * 96 + x0;

  for (int i = 0; i < 7; ++i) {
    float vrow[4][12];
    #pragma unroll
    for (int ch = 0; ch < 4; ++ch) {
      const unsigned int* lsrc = (const unsigned int*)&lv[(ch * 22 + (y + i)) * 104 + x0];
      #pragma unroll
      for (int t = 0; t < 6; ++t) {
        unsigned int u = lsrc[t];
        vrow[ch][2 * t]     = lo2f(u);
        vrow[ch][2 * t + 1] = hi2f(u);
      }
    }
    #pragma unroll
    for (int j = 0; j < 7; ++j) {
      const unsigned int* asrc = (const unsigned int*)
          &attn_c[((size_t)fc * 294 + head * 49 + i * 7 + j) * PIX + prow];
      unsigned int u0 = asrc[0], u1 = asrc[1], u2 = asrc[2];
      float av[6] = {lo2f(u0), hi2f(u0), lo2f(u1), hi2f(u1), lo2f(u2), hi2f(u2)};
      #pragma unroll
      for (int o = 0; o < 6; ++o)
        #pragma unroll
        for (int ch = 0; ch < 4; ++ch)
          acc[ch][o] += av[o] * vrow[ch][o + j];
    }
  }

  size_t obase = ((size_t)f * PIX + prow) * 96 + c0;
  #pragma unroll
  for (int o = 0; o < 6; ++o) {
    ushort4v r4;
    #pragma unroll
    for (int ch = 0; ch < 4; ++ch) r4[ch] = f2b(acc[ch][o]);
    *(ushort4v*)&out_t[obase + (size_t)o * 96] = r4;
  }
}

extern "C" void kernel_launch(void* const* d_in, const int* in_sizes, int n_in,
                              void* d_out, int out_size, void* d_ws, size_t ws_size,
                              hipStream_t stream) {
  const float* x    = (const float*)d_in[0];
  const float* ln_g = (const float*)d_in[1];
  const float* ln_b = (const float*)d_in[2];
  const float* w_qk = (const float*)d_in[3];
  const float* b_qk = (const float*)d_in[4];
  const float* w_v  = (const float*)d_in[5];
  const float* b_v  = (const float*)d_in[6];
  const float* w_a1 = (const float*)d_in[7];
  const float* b_a1 = (const float*)d_in[8];
  const float* w_a2 = (const float*)d_in[9];
  const float* b_a2 = (const float*)d_in[10];
  const float* g_mul= (const float*)d_in[11];
  const float* g_add= (const float*)d_in[12];
  const float* w_p  = (const float*)d_in[13];
  const float* b_p  = (const float*)d_in[14];

  char* ws = (char*)d_ws;
  u16*   W2    = (u16*)(ws + 0);
  float* bias2 = (float*)(ws + 61440);
  u16*   WA2   = (u16*)(ws + 62720);
  float* biasA2= (float*)(ws + 124160);
  u16*   WP    = (u16*)(ws + 125440);
  float* biasP = (float*)(ws + 150016);
  float* WC1   = (float*)(ws + 150528);
  u16*   xn_t  = (u16*)(ws + 225792);       // reused as a_t
  u16*   hbuf  = (u16*)(ws + 28537344);     // reused as out_t
  u16*   vbuf  = (u16*)(ws + 56848896);
  u16*   attnc = (u16*)(ws + 85160448);     // 8-frame attn chunk (8 x 294 x 9216)

  k_prep<<<365, 256, 0, stream>>>(w_qk, b_qk, w_v, b_v, w_a1, w_a2, b_a2, g_mul, g_add,
                                  w_p, b_p, W2, bias2, WA2, biasA2, WP, biasP, WC1);
  k_ln<<<576, 256, 0, stream>>>(x, ln_g, ln_b, xn_t);
  k_gemm<0><<<dim3(144, 5, 16), 256, 0, stream>>>(xn_t, W2, bias2, hbuf, vbuf,
                                                  nullptr, nullptr, 0);
  k_conv<<<dim3(24, 3, 16), 256, 0, stream>>>(hbuf, WC1, b_a1, xn_t /*a_t*/);
  for (int c = 0; c < 2; ++c) {
    k_gemm<1><<<dim3(144, 5, 8), 256, 0, stream>>>(xn_t /*a_t*/, WA2, biasA2,
                                                   attnc, nullptr, nullptr, nullptr, c * 8);
    k_aggr<<<dim3(24, 6, 8), 256, 0, stream>>>(attnc, vbuf, hbuf /*out_t*/, c * 8);
  }
  k_gemm<2><<<dim3(144, 2, 16), 256, 0, stream>>>(hbuf /*out_t*/, WP, biasP,
                                                  nullptr, nullptr, (float*)d_out, x, 0);
}